// Round 4
// baseline (188.564 us; speedup 1.0000x reference)
//
#include <hip/hip_runtime.h>

typedef _Float16 f16;
typedef f16   f16x4 __attribute__((ext_vector_type(4)));
typedef f16   f16x8 __attribute__((ext_vector_type(8)));
typedef float f32x4 __attribute__((ext_vector_type(4)));

#define MFMA16(a, b, c) __builtin_amdgcn_mfma_f32_16x16x32_f16((a), (b), (c), 0, 0, 0)

// ---- weight image offsets in d_ws (f16 units) ----
#define IMG_W1   0        // 32768: two halves of [128n][128k]
#define IMG_W2   32768    // 8192:  [64n][128k]
#define IMG_GW1  40960    // 2048:  [32n][64k]
#define IMG_EW1  43008    // 4*8192: [128n][64k]
#define IMG_EW2  75776    // 4*8192: [64n][128k]
#define IMG_SW   108544   // 4096:  [64n][64k]
#define IMG_HW1  112640   // 3*2048: [32n][64k]

__device__ __forceinline__ float silu_f(float v) {
    // v / (1+e^-v) with fast rcp: exp + add + rcp + mul (~4 instr vs ~10 for div)
    return v * __builtin_amdgcn_rcpf(1.0f + __expf(-v));
}

// ============ prep kernel: fp32 W[K][N] -> f16 img[n][k ^ ((n&7)<<3)] ============
__device__ void conv_seg(const float* __restrict__ src, f16* __restrict__ dst,
                         int K, int N, int tid, int nth) {
    for (int i = tid; i < K * N; i += nth) {
        const int k = i / N, n = i - k * N;
        dst[n * K + (k ^ ((n & 7) << 3))] = (f16)src[i];
    }
}

__global__ void prep_weights(const float* __restrict__ w1, const float* __restrict__ w2,
                             const float* __restrict__ gw1, const float* __restrict__ ew1,
                             const float* __restrict__ ew2, const float* __restrict__ sw,
                             const float* __restrict__ hw1, f16* __restrict__ ws) {
    const int tid = blockIdx.x * 256 + threadIdx.x;
    const int nth = gridDim.x * 256;
    conv_seg(w1,         ws + IMG_W1,         128, 128, tid, nth);
    conv_seg(w1 + 16384, ws + IMG_W1 + 16384, 128, 128, tid, nth);
    conv_seg(w2,         ws + IMG_W2,         128,  64, tid, nth);
    conv_seg(gw1,        ws + IMG_GW1,         64,  32, tid, nth);
    for (int e = 0; e < 4; ++e) {
        conv_seg(ew1 + e * 8192, ws + IMG_EW1 + e * 8192,  64, 128, tid, nth);
        conv_seg(ew2 + e * 8192, ws + IMG_EW2 + e * 8192, 128,  64, tid, nth);
    }
    conv_seg(sw, ws + IMG_SW, 64, 64, tid, nth);
    for (int h = 0; h < 3; ++h)
        conv_seg(hw1 + h * 2048, ws + IMG_HW1 + h * 2048, 64, 32, tid, nth);
}

// ============ async global->LDS staging (16B/lane, pre-swizzled source) ============
#define GLL16(g, l) __builtin_amdgcn_global_load_lds(                        \
    (const __attribute__((address_space(1))) void*)(g),                     \
    (__attribute__((address_space(3))) void*)(l), 16, 0, 0)

// 1KB chunks round-robined over 8 waves; LDS dest wave-uniform + lane*16.
template<int S_F16>
__device__ __forceinline__ void stage_img(const f16* __restrict__ g, f16* l,
                                          int wv, int lane) {
    constexpr int CHUNKS = (S_F16 * 2) / 1024;
    #pragma unroll
    for (int ch = 0; ch < CHUNKS; ++ch) {
        if ((ch & 7) == 0 || (ch & 7) == wv) {
            if ((ch & 7) == wv)
                GLL16((const char*)g + ch * 1024 + lane * 16, (char*)l + ch * 1024);
        }
    }
}

// ============ swizzle keys ============
// MODE 0: weight tiles (read-only)        key = (n&7)<<3
// MODE 1: ACT tiles, K=128 (read+write)   key = (r&15)<<3
// MODE 2: ACT tiles, K=64  (read+write)   key = (((r>>2)&3)<<1 | (r&1))<<3
__device__ __forceinline__ int swz_key(int mode, int r) {
    if (mode == 0) return (r & 7) << 3;
    if (mode == 1) return (r & 15) << 3;
    return ((((r >> 2) & 3) << 1) | (r & 1)) << 3;
}

template<int MODE>
__device__ __forceinline__ f16x8 ld_frag(const f16* base, int stride, int row_base, int k0) {
    const int lane = threadIdx.x & 63;
    const int r = row_base + (lane & 15);
    const int k = k0 + ((lane >> 4) << 3);
    return *(const f16x8*)(base + r * stride + (k ^ swz_key(MODE, r)));
}

template<int MODE>
__device__ __forceinline__ void st_frag(f16* base, int stride, int row_base, int col_base, f32x4 v) {
    const int lane = threadIdx.x & 63;
    const int c = col_base + (lane & 15);
    #pragma unroll
    for (int g = 0; g < 4; ++g) {
        const int r = row_base + ((lane >> 4) << 2) + g;
        base[r * stride + (c ^ swz_key(MODE, r))] = (f16)v[g];
    }
}

// coalesced x[128 rows][128 k-half] fp32 -> ACT1 f16, MODE-1 swizzled (512 threads)
__device__ __forceinline__ void stage_x(const float* __restrict__ xsrc, f16* ACT1, int half) {
    const int t = threadIdx.x;
    #pragma unroll
    for (int i = 0; i < 8; ++i) {
        const int idx4 = t + i * 512;
        const int r  = idx4 >> 5;
        const int kc = (idx4 & 31) << 2;
        const float4 v = *(const float4*)(xsrc + (long)r * 256 + half * 128 + kc);
        f16x4 o; o[0] = (f16)v.x; o[1] = (f16)v.y; o[2] = (f16)v.z; o[3] = (f16)v.w;
        *(f16x4*)(ACT1 + r * 128 + (kc ^ ((r & 15) << 3))) = o;
    }
}

__device__ __forceinline__ f32x4 reduce16(f32x4 v) {
    #pragma unroll
    for (int m = 1; m <= 8; m <<= 1) {
        f32x4 o;
        #pragma unroll
        for (int i = 0; i < 4; ++i) o[i] = __shfl_xor(v[i], m, 64);
        v += o;
    }
    return v;
}

__global__ __launch_bounds__(512, 4)
void fused_net_mfma(const float* __restrict__ x,   const f16* __restrict__ wsp,
                    const float* __restrict__ b1,  const float* __restrict__ lng,
                    const float* __restrict__ lnb, const float* __restrict__ b2,
                    const float* __restrict__ eb1, const float* __restrict__ eb2,
                    const float* __restrict__ gb1, const float* __restrict__ gw2,
                    const float* __restrict__ gb2, const float* __restrict__ sb,
                    const float* __restrict__ hb1, const float* __restrict__ hw2,
                    const float* __restrict__ hb2, float* __restrict__ out)
{
    __shared__ __align__(16) f16 lds[40960];   // 80 KB -> 2 blocks/CU, 16 waves/CU
    f16* ACT1 = lds;            // [128][128] MODE1 (x, LN, E1; feat as [128][64] MODE2)
    f16* ACT2 = lds + 16384;    // [128][64]  MODE2 (hb, moe)
    f16* WA   = lds + 24576;    // weight slot A (stem1 uses WA..WB as one 32KB tile)
    f16* WB   = lds + 32768;    // weight slot B

    const int lane = threadIdx.x & 63;
    const int wv   = threadIdx.x >> 6;          // 0..7
    const int c    = lane & 15;
    const long blockRow = (long)blockIdx.x * 128;
    const int waveRow = wv * 16;                // each wave owns 16 rows
    const float* xblk = x + blockRow * 256;

    // ---- P0: stage w1 half0 (32KB across WA+WB) + x half0 ----
    stage_img<16384>(wsp + IMG_W1, WA, wv, lane);
    stage_x(xblk, ACT1, 0);
    __syncthreads();

    // ---- stem1: h = x @ w1 + b1 (K=256 in halves, N=128) ----
    f32x4 acc[8];
    #pragma unroll
    for (int n = 0; n < 8; ++n) {
        const float bv = b1[n * 16 + c];
        f32x4 t = {bv, bv, bv, bv};
        acc[n] = t;
    }
    #pragma unroll
    for (int ks = 0; ks < 4; ++ks) {
        const f16x8 a0 = ld_frag<1>(ACT1, 128, waveRow, ks * 32);
        #pragma unroll
        for (int n = 0; n < 8; ++n) {
            const f16x8 b = ld_frag<0>(WA, 128, n * 16, ks * 32);
            acc[n] = MFMA16(a0, b, acc[n]);
        }
    }
    __syncthreads();   // W + ACT1 free

    // ---- P2: stage w1 half1 + x half1 ----
    stage_img<16384>(wsp + IMG_W1 + 16384, WA, wv, lane);
    stage_x(xblk, ACT1, 1);
    __syncthreads();

    #pragma unroll
    for (int ks = 0; ks < 4; ++ks) {
        const f16x8 a0 = ld_frag<1>(ACT1, 128, waveRow, ks * 32);
        #pragma unroll
        for (int n = 0; n < 8; ++n) {
            const f16x8 b = ld_frag<0>(WA, 128, n * 16, ks * 32);
            acc[n] = MFMA16(a0, b, acc[n]);
        }
    }

    // ---- LayerNorm(128) + SiLU -> ACT1 (own rows; intra-wave) ----
    {
        f32x4 s = {0, 0, 0, 0}, q = {0, 0, 0, 0};
        #pragma unroll
        for (int n = 0; n < 8; ++n) { s += acc[n]; q += acc[n] * acc[n]; }
        s = reduce16(s); q = reduce16(q);
        const f32x4 mu = s * 0.0078125f;
        f32x4 rs;
        #pragma unroll
        for (int g = 0; g < 4; ++g) {
            const float var = q[g] * 0.0078125f - mu[g] * mu[g];
            rs[g] = rsqrtf(var + 1e-5f);
        }
        #pragma unroll
        for (int n = 0; n < 8; ++n) {
            const float gg = lng[n * 16 + c], bb = lnb[n * 16 + c];
            f32x4 v;
            #pragma unroll
            for (int g = 0; g < 4; ++g)
                v[g] = silu_f((acc[n][g] - mu[g]) * rs[g] * gg + bb);
            st_frag<1>(ACT1, 128, waveRow, n * 16, v);
        }
    }
    __syncthreads();   // all waves' WA reads done

    // ---- P4: stage w2 -> WA, gw1 -> WB ----
    stage_img<8192>(wsp + IMG_W2,  WA, wv, lane);
    stage_img<2048>(wsp + IMG_GW1, WB, wv, lane);
    __syncthreads();

    // ---- stem2: hb = silu(LN @ w2 + b2) (K=128, N=64) -> ACT2 ----
    {
        f32x4 a2[4];
        #pragma unroll
        for (int n = 0; n < 4; ++n) {
            const float bv = b2[n * 16 + c];
            f32x4 t = {bv, bv, bv, bv};
            a2[n] = t;
        }
        #pragma unroll
        for (int ks = 0; ks < 4; ++ks) {
            const f16x8 a0 = ld_frag<1>(ACT1, 128, waveRow, ks * 32);
            #pragma unroll
            for (int n = 0; n < 4; ++n) {
                const f16x8 b = ld_frag<0>(WA, 128, n * 16, ks * 32);
                a2[n] = MFMA16(a0, b, a2[n]);
            }
        }
        #pragma unroll
        for (int n = 0; n < 4; ++n) {
            f32x4 v;
            #pragma unroll
            for (int g = 0; g < 4; ++g) v[g] = silu_f(a2[n][g]);
            st_frag<2>(ACT2, 64, waveRow, n * 16, v);
        }
    }

    // ---- gate: softmax(silu(hb@gw1+gb1)@gw2+gb2) (own ACT2 rows) ----
    f32x4 gwt[4];   // [g] -> 4 gate weights in vector lanes
    {
        f32x4 ag[2];
        #pragma unroll
        for (int n = 0; n < 2; ++n) {
            const float bv = gb1[n * 16 + c];
            f32x4 t = {bv, bv, bv, bv};
            ag[n] = t;
        }
        #pragma unroll
        for (int ks = 0; ks < 2; ++ks) {
            const f16x8 a0 = ld_frag<2>(ACT2, 64, waveRow, ks * 32);
            #pragma unroll
            for (int n = 0; n < 2; ++n) {
                const f16x8 b = ld_frag<0>(WB, 64, n * 16, ks * 32);
                ag[n] = MFMA16(a0, b, ag[n]);
            }
        }
        const f32x4 gb2v = *(const f32x4*)gb2;
        f32x4 pg[4] = {{0,0,0,0},{0,0,0,0},{0,0,0,0},{0,0,0,0}};
        #pragma unroll
        for (int n = 0; n < 2; ++n) {
            const int j = n * 16 + c;
            const f32x4 w4 = *(const f32x4*)(gw2 + j * 4);
            #pragma unroll
            for (int g = 0; g < 4; ++g)
                pg[g] += silu_f(ag[n][g]) * w4;
        }
        #pragma unroll
        for (int g = 0; g < 4; ++g) {
            f32x4 l = reduce16(pg[g]) + gb2v;
            const float mx = fmaxf(fmaxf(l[0], l[1]), fmaxf(l[2], l[3]));
            f32x4 ee;
            #pragma unroll
            for (int o = 0; o < 4; ++o) ee[o] = __expf(l[o] - mx);
            const float inv = __builtin_amdgcn_rcpf(ee[0] + ee[1] + ee[2] + ee[3]);
            gwt[g] = ee * inv;
        }
    }
    __syncthreads();   // WA, WB free

    // ---- P6: stage ew1[0] -> WA ----
    stage_img<8192>(wsp + IMG_EW1, WA, wv, lane);
    __syncthreads();

    // ---- 4 experts, fully unrolled (gwt[g][e] needs static e) ----
    f32x4 moe[4] = {{0,0,0,0},{0,0,0,0},{0,0,0,0},{0,0,0,0}};
    #pragma unroll
    for (int e = 0; e < 4; ++e) {
        stage_img<8192>(wsp + IMG_EW2 + e * 8192, WB, wv, lane);   // hides under e1
        // e1: E1 = silu(hb @ ew1 + eb1) (K=64, N=128) in two N-halves
        #pragma unroll
        for (int mh = 0; mh < 2; ++mh) {
            f32x4 a1acc[4];
            #pragma unroll
            for (int n = 0; n < 4; ++n) {
                const float bv = eb1[e * 128 + mh * 64 + n * 16 + c];
                f32x4 t = {bv, bv, bv, bv};
                a1acc[n] = t;
            }
            #pragma unroll
            for (int ks = 0; ks < 2; ++ks) {
                const f16x8 a0 = ld_frag<2>(ACT2, 64, waveRow, ks * 32);
                #pragma unroll
                for (int n = 0; n < 4; ++n) {
                    const f16x8 b = ld_frag<0>(WA, 64, mh * 64 + n * 16, ks * 32);
                    a1acc[n] = MFMA16(a0, b, a1acc[n]);
                }
            }
            #pragma unroll
            for (int n = 0; n < 4; ++n) {
                f32x4 v;
                #pragma unroll
                for (int g = 0; g < 4; ++g) v[g] = silu_f(a1acc[n][g]);
                st_frag<1>(ACT1, 128, waveRow, mh * 64 + n * 16, v);
            }
        }
        __syncthreads();   // WA free; WB (ew2) staged
        if (e < 3) stage_img<8192>(wsp + IMG_EW1 + (e + 1) * 8192, WA, wv, lane); // hides under e2
        // e2: moe += gate[e] * silu(E1 @ ew2 + eb2) (K=128, N=64)
        f32x4 a2acc[4];
        #pragma unroll
        for (int n = 0; n < 4; ++n) {
            const float bv = eb2[e * 64 + n * 16 + c];
            f32x4 t = {bv, bv, bv, bv};
            a2acc[n] = t;
        }
        #pragma unroll
        for (int ks = 0; ks < 4; ++ks) {
            const f16x8 a0 = ld_frag<1>(ACT1, 128, waveRow, ks * 32);
            #pragma unroll
            for (int n = 0; n < 4; ++n) {
                const f16x8 b = ld_frag<0>(WB, 128, n * 16, ks * 32);
                a2acc[n] = MFMA16(a0, b, a2acc[n]);
            }
        }
        #pragma unroll
        for (int n = 0; n < 4; ++n)
            #pragma unroll
            for (int g = 0; g < 4; ++g)
                moe[n][g] += silu_f(a2acc[n][g]) * gwt[g][e];
        __syncthreads();   // WB free; WA (next ew1) staged
    }

    // ---- moe -> ACT2 (hb dead); stage sw -> WA, hw1 -> WB ----
    #pragma unroll
    for (int n = 0; n < 4; ++n)
        st_frag<2>(ACT2, 64, waveRow, n * 16, moe[n]);
    stage_img<4096>(wsp + IMG_SW,  WA, wv, lane);
    stage_img<6144>(wsp + IMG_HW1, WB, wv, lane);
    __syncthreads();

    // ---- shared: feat = silu(moe @ sw + sb) (K=64, N=64) -> ACT1 [128][64] ----
    {
        f32x4 as[4];
        #pragma unroll
        for (int n = 0; n < 4; ++n) {
            const float bv = sb[n * 16 + c];
            f32x4 t = {bv, bv, bv, bv};
            as[n] = t;
        }
        #pragma unroll
        for (int ks = 0; ks < 2; ++ks) {
            const f16x8 a0 = ld_frag<2>(ACT2, 64, waveRow, ks * 32);
            #pragma unroll
            for (int n = 0; n < 4; ++n) {
                const f16x8 b = ld_frag<0>(WA, 64, n * 16, ks * 32);
                as[n] = MFMA16(a0, b, as[n]);
            }
        }
        #pragma unroll
        for (int n = 0; n < 4; ++n) {
            f32x4 v;
            #pragma unroll
            for (int g = 0; g < 4; ++g) v[g] = silu_f(as[n][g]);
            st_frag<2>(ACT1, 64, waveRow, n * 16, v);
        }
    }

    // ---- heads (own-wave ACT1 rows; intra-wave) ----
    {
        f32x4 ah[6];
        #pragma unroll
        for (int n = 0; n < 6; ++n) {
            const float bv = hb1[(n >> 1) * 32 + (n & 1) * 16 + c];
            f32x4 t = {bv, bv, bv, bv};
            ah[n] = t;
        }
        #pragma unroll
        for (int ks = 0; ks < 2; ++ks) {
            const f16x8 a0 = ld_frag<2>(ACT1, 64, waveRow, ks * 32);
            #pragma unroll
            for (int n = 0; n < 6; ++n) {
                const f16x8 b = ld_frag<0>(WB + (n >> 1) * 2048, 64, (n & 1) * 16, ks * 32);
                ah[n] = MFMA16(a0, b, ah[n]);
            }
        }
        const float hb2_0 = hb2[0], hb2_1 = hb2[1], hb2_2 = hb2[2];
        f32x4 ph[3] = {{0,0,0,0},{0,0,0,0},{0,0,0,0}};
        #pragma unroll
        for (int n = 0; n < 6; ++n) {
            const int head = n >> 1;
            const int j = (n & 1) * 16 + c;
            const float w2v = hw2[head * 32 + j];
            #pragma unroll
            for (int g = 0; g < 4; ++g)
                ph[head][g] += silu_f(ah[n][g]) * w2v;
        }
        #pragma unroll
        for (int h = 0; h < 3; ++h) ph[h] = reduce16(ph[h]);
        #pragma unroll
        for (int g = 0; g < 4; ++g) {
            const long row = blockRow + waveRow + ((lane >> 4) << 2) + g;
            if (c < 3) {
                const float r0 = ph[0][g] + hb2_0;
                const float r1 = ph[1][g] + hb2_1;
                const float r2 = ph[2][g] + hb2_2;
                out[row * 3 + c] = (c == 0) ? r0 : ((c == 1) ? r1 : r2);
            }
        }
    }
}

extern "C" void kernel_launch(void* const* d_in, const int* in_sizes, int n_in,
                              void* d_out, int out_size, void* d_ws, size_t ws_size,
                              hipStream_t stream) {
    const float* x    = (const float*)d_in[0];
    const float* w1   = (const float*)d_in[1];
    const float* b1   = (const float*)d_in[2];
    const float* lng  = (const float*)d_in[3];
    const float* lnb  = (const float*)d_in[4];
    const float* w2   = (const float*)d_in[5];
    const float* b2   = (const float*)d_in[6];
    const float* ew1  = (const float*)d_in[7];
    const float* eb1  = (const float*)d_in[8];
    const float* ew2  = (const float*)d_in[9];
    const float* eb2  = (const float*)d_in[10];
    const float* gw1  = (const float*)d_in[11];
    const float* gb1  = (const float*)d_in[12];
    const float* gw2  = (const float*)d_in[13];
    const float* gb2  = (const float*)d_in[14];
    const float* sw   = (const float*)d_in[15];
    const float* sb   = (const float*)d_in[16];
    const float* hw1  = (const float*)d_in[17];
    const float* hb1  = (const float*)d_in[18];
    const float* hw2  = (const float*)d_in[19];
    const float* hb2  = (const float*)d_in[20];
    float* out = (float*)d_out;
    f16* ws = (f16*)d_ws;

    hipLaunchKernelGGL(prep_weights, dim3(64), dim3(256), 0, stream,
                       w1, w2, gw1, ew1, ew2, sw, hw1, ws);

    const int B = in_sizes[0] / 256;
    const int grid = B / 128;
    hipLaunchKernelGGL(fused_net_mfma, dim3(grid), dim3(512), 0, stream,
                       x, ws, b1, lng, lnb, b2, eb1, eb2, gb1, gw2, gb2,
                       sb, hb1, hw2, hb2, out);
}

// Round 5
// 109.128 us; speedup vs baseline: 1.7279x; 1.7279x over previous
//
#include <hip/hip_runtime.h>

typedef _Float16 f16;
typedef f16   f16x4 __attribute__((ext_vector_type(4)));
typedef f16   f16x8 __attribute__((ext_vector_type(8)));
typedef float f32x4 __attribute__((ext_vector_type(4)));

#define MFMA16(a, b, c) __builtin_amdgcn_mfma_f32_16x16x32_f16((a), (b), (c), 0, 0, 0)

// ---- weight image offsets in d_ws (f16 units) ----
// w1: 4 quarters (kh,nh) each [64n][128k] = 8192
#define IMG_W1   0        // 32768
#define IMG_W2   32768    // 8192:  [64n][128k]
#define IMG_GW1  40960    // 2048:  [32n][64k]
#define IMG_EW1  43008    // 4 e * 2 mh * [64n][64k]=4096 -> 32768
#define IMG_EW2  75776    // 4 e * 2 kh * [64n][64k]=4096 -> 32768
#define IMG_SW   108544   // 4096:  [64n][64k]
#define IMG_HW1  112640   // 3 * [32n][64k]=2048 -> 6144

__device__ __forceinline__ float silu_f(float v) {
    return v * __builtin_amdgcn_rcpf(1.0f + __expf(-v));
}

// ============ prep: fp32 src[K][N] (ld srcN) -> f16 img[n][k ^ ((n&7)<<3)] ============
__device__ void conv_blk(const float* __restrict__ src, f16* __restrict__ dst,
                         int srcN, int k0, int n0, int KB, int NB, int tid, int nth) {
    for (int i = tid; i < KB * NB; i += nth) {
        const int kk = i / NB, nn = i - kk * NB;
        dst[nn * KB + (kk ^ ((nn & 7) << 3))] = (f16)src[(long)(k0 + kk) * srcN + n0 + nn];
    }
}

__global__ void prep_weights(const float* __restrict__ w1, const float* __restrict__ w2,
                             const float* __restrict__ gw1, const float* __restrict__ ew1,
                             const float* __restrict__ ew2, const float* __restrict__ sw,
                             const float* __restrict__ hw1, f16* __restrict__ ws) {
    const int tid = blockIdx.x * 256 + threadIdx.x;
    const int nth = gridDim.x * 256;
    for (int kh = 0; kh < 2; ++kh)
        for (int nh = 0; nh < 2; ++nh)
            conv_blk(w1, ws + IMG_W1 + (kh * 2 + nh) * 8192, 128, kh * 128, nh * 64, 128, 64, tid, nth);
    conv_blk(w2,  ws + IMG_W2,  64, 0, 0, 128, 64, tid, nth);
    conv_blk(gw1, ws + IMG_GW1, 32, 0, 0,  64, 32, tid, nth);
    for (int e = 0; e < 4; ++e)
        for (int h = 0; h < 2; ++h) {
            conv_blk(ew1 + e * 8192, ws + IMG_EW1 + (e * 2 + h) * 4096, 128, 0, h * 64, 64, 64, tid, nth);
            conv_blk(ew2 + e * 8192, ws + IMG_EW2 + (e * 2 + h) * 4096,  64, h * 64, 0, 64, 64, tid, nth);
        }
    conv_blk(sw, ws + IMG_SW, 64, 0, 0, 64, 64, tid, nth);
    for (int h = 0; h < 3; ++h)
        conv_blk(hw1 + h * 2048, ws + IMG_HW1 + h * 2048, 32, 0, 0, 64, 32, tid, nth);
}

// ============ async global->LDS staging (16B/lane, contiguous wave quarters) ============
#define GLL16(g, l) __builtin_amdgcn_global_load_lds(                        \
    (const __attribute__((address_space(1))) void*)(g),                     \
    (__attribute__((address_space(3))) void*)(l), 16, 0, 0)

template<int S_F16>
__device__ __forceinline__ void stage_img(const f16* __restrict__ g, f16* l,
                                          int wv, int lane) {
    constexpr int QB = (S_F16 * 2) / 4;   // bytes per wave quarter
    constexpr int CALLS = QB / 1024;      // 64 lanes * 16B per call
    const char* gs = (const char*)g + wv * QB + lane * 16;
    char* ls = (char*)l + wv * QB;        // wave-uniform base; HW adds lane*16
    #pragma unroll
    for (int i = 0; i < CALLS; ++i)
        GLL16(gs + i * 1024, ls + i * 1024);
}

// ============ swizzle keys ============
// MODE 0: weight imgs (read-only)          key = (n&7)<<3
// MODE 1: XACT [128][128] (x staging)      key = (r&15)<<3
// MODE 2: ACT [128][64] (read+write)       key = (((r>>2)&3)<<1 | (r&1))<<3
__device__ __forceinline__ int swz_key(int mode, int r) {
    if (mode == 0) return (r & 7) << 3;
    if (mode == 1) return (r & 15) << 3;
    return ((((r >> 2) & 3) << 1) | (r & 1)) << 3;
}

template<int MODE>
__device__ __forceinline__ f16x8 ld_frag(const f16* base, int stride, int row_base, int k0) {
    const int lane = threadIdx.x & 63;
    const int r = row_base + (lane & 15);
    const int k = k0 + ((lane >> 4) << 3);
    return *(const f16x8*)(base + r * stride + (k ^ swz_key(MODE, r)));
}

template<int MODE>
__device__ __forceinline__ void st_frag(f16* base, int stride, int row_base, int col_base, f32x4 v) {
    const int lane = threadIdx.x & 63;
    const int c = col_base + (lane & 15);
    #pragma unroll
    for (int g = 0; g < 4; ++g) {
        const int r = row_base + ((lane >> 4) << 2) + g;
        base[r * stride + (c ^ swz_key(MODE, r))] = (f16)v[g];
    }
}

// coalesced x[128 rows][128 k-half] fp32 -> XACT f16 [128][128] MODE1 (256 threads)
__device__ __forceinline__ void stage_x(const float* __restrict__ xsrc, f16* XACT, int half) {
    const int t = threadIdx.x;
    #pragma unroll 8
    for (int i = 0; i < 16; ++i) {
        const int idx4 = t + i * 256;
        const int r  = idx4 >> 5;
        const int kc = (idx4 & 31) << 2;
        const float4 v = *(const float4*)(xsrc + (long)r * 256 + half * 128 + kc);
        f16x4 o; o[0] = (f16)v.x; o[1] = (f16)v.y; o[2] = (f16)v.z; o[3] = (f16)v.w;
        *(f16x4*)(XACT + r * 128 + (kc ^ ((r & 15) << 3))) = o;
    }
}

__device__ __forceinline__ f32x4 reduce16(f32x4 v) {
    #pragma unroll
    for (int m = 1; m <= 8; m <<= 1) {
        f32x4 o;
        #pragma unroll
        for (int i = 0; i < 4; ++i) o[i] = __shfl_xor(v[i], m, 64);
        v += o;
    }
    return v;
}

__global__ __launch_bounds__(256, 3)
void fused_net_mfma(const float* __restrict__ x,   const f16* __restrict__ wsp,
                    const float* __restrict__ b1,  const float* __restrict__ lng,
                    const float* __restrict__ lnb, const float* __restrict__ b2,
                    const float* __restrict__ eb1, const float* __restrict__ eb2,
                    const float* __restrict__ gb1, const float* __restrict__ gw2,
                    const float* __restrict__ gb2, const float* __restrict__ sb,
                    const float* __restrict__ hb1, const float* __restrict__ hw2,
                    const float* __restrict__ hb2, float* __restrict__ out)
{
    __shared__ __align__(16) f16 lds[26624];   // 52 KB -> 3 blocks/CU
    f16* XACT = lds;            // [128][128] MODE1, stem1 only
    f16* ACT1 = lds;            // [128][64] MODE2 (LN halves, E1 halves, feat)
    f16* ACT2 = lds + 8192;     // [128][64] MODE2 (hb, moe)
    f16* W    = lds + 16384;    // 8192 f16 weight slot (W0 = W, W1 = W+4096)
    f16* G    = lds + 24576;    // 2048 f16 (gw1; later hw1[2])

    const int lane = threadIdx.x & 63;
    const int wv   = threadIdx.x >> 6;
    const int c    = lane & 15;
    const long blockRow = (long)blockIdx.x * 128;
    const int waveRow = wv * 32;                 // each wave owns 32 rows (2 M-frags)
    const float* xblk = x + blockRow * 256;

    // ================= stem1: h = x @ w1 + b1 (K=256, N=128) =================
    f32x4 acc[2][8];
    #pragma unroll
    for (int n = 0; n < 8; ++n) {
        const float bv = b1[n * 16 + c];
        f32x4 t = {bv, bv, bv, bv};
        acc[0][n] = t; acc[1][n] = t;
    }
    #pragma unroll
    for (int kh = 0; kh < 2; ++kh) {
        if (kh) __syncthreads();                 // prior XACT/W reads done
        stage_x(xblk, XACT, kh);
        stage_img<8192>(wsp + IMG_W1 + kh * 16384, W, wv, lane);   // quarter (kh,0)
        __syncthreads();
        f16x8 af[2][4];                          // A-frags in regs, reused for both nh
        #pragma unroll
        for (int m = 0; m < 2; ++m)
            #pragma unroll
            for (int ks = 0; ks < 4; ++ks)
                af[m][ks] = ld_frag<1>(XACT, 128, waveRow + m * 16, ks * 32);
        #pragma unroll
        for (int ks = 0; ks < 4; ++ks)
            #pragma unroll
            for (int n = 0; n < 4; ++n) {
                const f16x8 b = ld_frag<0>(W, 128, n * 16, ks * 32);
                acc[0][n] = MFMA16(af[0][ks], b, acc[0][n]);
                acc[1][n] = MFMA16(af[1][ks], b, acc[1][n]);
            }
        __syncthreads();
        stage_img<8192>(wsp + IMG_W1 + kh * 16384 + 8192, W, wv, lane);  // quarter (kh,1)
        __syncthreads();
        #pragma unroll
        for (int ks = 0; ks < 4; ++ks)
            #pragma unroll
            for (int n = 0; n < 4; ++n) {
                const f16x8 b = ld_frag<0>(W, 128, n * 16, ks * 32);
                acc[0][4 + n] = MFMA16(af[0][ks], b, acc[0][4 + n]);
                acc[1][4 + n] = MFMA16(af[1][ks], b, acc[1][4 + n]);
            }
    }

    // ---- LN statistics (regs) ----
    f32x4 mu[2], rs[2];
    #pragma unroll
    for (int m = 0; m < 2; ++m) {
        f32x4 s = {0, 0, 0, 0}, q = {0, 0, 0, 0};
        #pragma unroll
        for (int n = 0; n < 8; ++n) { s += acc[m][n]; q += acc[m][n] * acc[m][n]; }
        s = reduce16(s); q = reduce16(q);
        mu[m] = s * 0.0078125f;
        #pragma unroll
        for (int g = 0; g < 4; ++g) {
            const float var = q[g] * 0.0078125f - mu[m][g] * mu[m][g];
            rs[m][g] = rsqrtf(var + 1e-5f);
        }
    }
    __syncthreads();                              // all W reads done
    stage_img<8192>(wsp + IMG_W2,  W, wv, lane);
    stage_img<2048>(wsp + IMG_GW1, G, wv, lane);
    __syncthreads();

    // ================= stem2 in two K-halves: hb = silu(LN @ w2 + b2) =================
    f32x4 a2[2][4];
    #pragma unroll
    for (int n = 0; n < 4; ++n) {
        const float bv = b2[n * 16 + c];
        f32x4 t = {bv, bv, bv, bv};
        a2[0][n] = t; a2[1][n] = t;
    }
    #pragma unroll
    for (int half = 0; half < 2; ++half) {
        #pragma unroll
        for (int m = 0; m < 2; ++m)
            #pragma unroll
            for (int n = 0; n < 4; ++n) {
                const int j = half * 64 + n * 16 + c;      // LN feature index
                const float gg = lng[j], bb = lnb[j];
                f32x4 v;
                #pragma unroll
                for (int g = 0; g < 4; ++g)
                    v[g] = silu_f((acc[m][half * 4 + n][g] - mu[m][g]) * rs[m][g] * gg + bb);
                st_frag<2>(ACT1, 64, waveRow + m * 16, n * 16, v);   // own rows
            }
        #pragma unroll
        for (int ks = 0; ks < 2; ++ks) {
            const f16x8 a0 = ld_frag<2>(ACT1, 64, waveRow,      ks * 32);
            const f16x8 a1 = ld_frag<2>(ACT1, 64, waveRow + 16, ks * 32);
            #pragma unroll
            for (int n = 0; n < 4; ++n) {
                const f16x8 b = ld_frag<0>(W, 128, n * 16, half * 64 + ks * 32);
                a2[0][n] = MFMA16(a0, b, a2[0][n]);
                a2[1][n] = MFMA16(a1, b, a2[1][n]);
            }
        }
    }
    #pragma unroll
    for (int m = 0; m < 2; ++m)
        #pragma unroll
        for (int n = 0; n < 4; ++n) {
            f32x4 v;
            #pragma unroll
            for (int g = 0; g < 4; ++g) v[g] = silu_f(a2[m][n][g]);
            st_frag<2>(ACT2, 64, waveRow + m * 16, n * 16, v);       // hb, own rows
        }

    // ================= gate (own ACT2 rows + G) =================
    f32x4 gwt[2][4];
    {
        f32x4 ag[2][2];
        #pragma unroll
        for (int n = 0; n < 2; ++n) {
            const float bv = gb1[n * 16 + c];
            f32x4 t = {bv, bv, bv, bv};
            ag[0][n] = t; ag[1][n] = t;
        }
        #pragma unroll
        for (int ks = 0; ks < 2; ++ks) {
            const f16x8 a0 = ld_frag<2>(ACT2, 64, waveRow,      ks * 32);
            const f16x8 a1 = ld_frag<2>(ACT2, 64, waveRow + 16, ks * 32);
            #pragma unroll
            for (int n = 0; n < 2; ++n) {
                const f16x8 b = ld_frag<0>(G, 64, n * 16, ks * 32);
                ag[0][n] = MFMA16(a0, b, ag[0][n]);
                ag[1][n] = MFMA16(a1, b, ag[1][n]);
            }
        }
        const f32x4 gb2v = *(const f32x4*)gb2;
        #pragma unroll
        for (int m = 0; m < 2; ++m) {
            f32x4 pg[4] = {{0,0,0,0},{0,0,0,0},{0,0,0,0},{0,0,0,0}};
            #pragma unroll
            for (int n = 0; n < 2; ++n) {
                const int j = n * 16 + c;
                const f32x4 w4 = *(const f32x4*)(gw2 + j * 4);
                #pragma unroll
                for (int g = 0; g < 4; ++g)
                    pg[g] += silu_f(ag[m][n][g]) * w4;
            }
            #pragma unroll
            for (int g = 0; g < 4; ++g) {
                f32x4 l = reduce16(pg[g]) + gb2v;
                const float mx = fmaxf(fmaxf(l[0], l[1]), fmaxf(l[2], l[3]));
                f32x4 ee;
                #pragma unroll
                for (int o = 0; o < 4; ++o) ee[o] = __expf(l[o] - mx);
                const float inv = __builtin_amdgcn_rcpf(ee[0] + ee[1] + ee[2] + ee[3]);
                gwt[m][g] = ee * inv;
            }
        }
    }

    // ================= 4 experts, each in two halves (E1 never full-width) =================
    f32x4 moe[2][4] = {{{0,0,0,0},{0,0,0,0},{0,0,0,0},{0,0,0,0}},
                       {{0,0,0,0},{0,0,0,0},{0,0,0,0},{0,0,0,0}}};
    #pragma unroll
    for (int e = 0; e < 4; ++e) {
        f32x4 a2acc[2][4];
        #pragma unroll
        for (int n = 0; n < 4; ++n) {
            const float bv = eb2[e * 64 + n * 16 + c];
            f32x4 t = {bv, bv, bv, bv};
            a2acc[0][n] = t; a2acc[1][n] = t;
        }
        #pragma unroll
        for (int mh = 0; mh < 2; ++mh) {
            __syncthreads();                                     // prior W reads done
            stage_img<4096>(wsp + IMG_EW1 + (e * 2 + mh) * 4096, W,        wv, lane);
            stage_img<4096>(wsp + IMG_EW2 + (e * 2 + mh) * 4096, W + 4096, wv, lane);
            __syncthreads();
            // e1 half: [B,64] @ [64,64] -> silu -> ACT1 (own rows)
            f32x4 a1acc[2][4];
            #pragma unroll
            for (int n = 0; n < 4; ++n) {
                const float bv = eb1[e * 128 + mh * 64 + n * 16 + c];
                f32x4 t = {bv, bv, bv, bv};
                a1acc[0][n] = t; a1acc[1][n] = t;
            }
            #pragma unroll
            for (int ks = 0; ks < 2; ++ks) {
                const f16x8 a0 = ld_frag<2>(ACT2, 64, waveRow,      ks * 32);
                const f16x8 a1 = ld_frag<2>(ACT2, 64, waveRow + 16, ks * 32);
                #pragma unroll
                for (int n = 0; n < 4; ++n) {
                    const f16x8 b = ld_frag<0>(W, 64, n * 16, ks * 32);
                    a1acc[0][n] = MFMA16(a0, b, a1acc[0][n]);
                    a1acc[1][n] = MFMA16(a1, b, a1acc[1][n]);
                }
            }
            #pragma unroll
            for (int m = 0; m < 2; ++m)
                #pragma unroll
                for (int n = 0; n < 4; ++n) {
                    f32x4 v;
                    #pragma unroll
                    for (int g = 0; g < 4; ++g) v[g] = silu_f(a1acc[m][n][g]);
                    st_frag<2>(ACT1, 64, waveRow + m * 16, n * 16, v);
                }
            // e2 partial over this K-half (own rows)
            #pragma unroll
            for (int ks = 0; ks < 2; ++ks) {
                const f16x8 a0 = ld_frag<2>(ACT1, 64, waveRow,      ks * 32);
                const f16x8 a1 = ld_frag<2>(ACT1, 64, waveRow + 16, ks * 32);
                #pragma unroll
                for (int n = 0; n < 4; ++n) {
                    const f16x8 b = ld_frag<0>(W + 4096, 64, n * 16, ks * 32);
                    a2acc[0][n] = MFMA16(a0, b, a2acc[0][n]);
                    a2acc[1][n] = MFMA16(a1, b, a2acc[1][n]);
                }
            }
        }
        #pragma unroll
        for (int m = 0; m < 2; ++m)
            #pragma unroll
            for (int n = 0; n < 4; ++n)
                #pragma unroll
                for (int g = 0; g < 4; ++g)
                    moe[m][n][g] += silu_f(a2acc[m][n][g]) * gwt[m][g][e];
    }

    // ---- moe -> ACT2 (hb dead, own rows); stage sw + hw1 ----
    #pragma unroll
    for (int m = 0; m < 2; ++m)
        #pragma unroll
        for (int n = 0; n < 4; ++n)
            st_frag<2>(ACT2, 64, waveRow + m * 16, n * 16, moe[m][n]);
    __syncthreads();                              // expert W reads done
    stage_img<4096>(wsp + IMG_SW,         W,        wv, lane);
    stage_img<2048>(wsp + IMG_HW1,        W + 4096, wv, lane);   // head0
    stage_img<2048>(wsp + IMG_HW1 + 2048, W + 6144, wv, lane);   // head1
    stage_img<2048>(wsp + IMG_HW1 + 4096, G,        wv, lane);   // head2 (gw1 dead)
    __syncthreads();

    // ================= shared: feat = silu(moe @ sw + sb) -> ACT1 =================
    {
        f32x4 as[2][4];
        #pragma unroll
        for (int n = 0; n < 4; ++n) {
            const float bv = sb[n * 16 + c];
            f32x4 t = {bv, bv, bv, bv};
            as[0][n] = t; as[1][n] = t;
        }
        #pragma unroll
        for (int ks = 0; ks < 2; ++ks) {
            const f16x8 a0 = ld_frag<2>(ACT2, 64, waveRow,      ks * 32);
            const f16x8 a1 = ld_frag<2>(ACT2, 64, waveRow + 16, ks * 32);
            #pragma unroll
            for (int n = 0; n < 4; ++n) {
                const f16x8 b = ld_frag<0>(W, 64, n * 16, ks * 32);
                as[0][n] = MFMA16(a0, b, as[0][n]);
                as[1][n] = MFMA16(a1, b, as[1][n]);
            }
        }
        #pragma unroll
        for (int m = 0; m < 2; ++m)
            #pragma unroll
            for (int n = 0; n < 4; ++n) {
                f32x4 v;
                #pragma unroll
                for (int g = 0; g < 4; ++g) v[g] = silu_f(as[m][n][g]);
                st_frag<2>(ACT1, 64, waveRow + m * 16, n * 16, v);
            }
    }

    // ================= heads (own ACT1 rows) =================
    {
        f32x4 ah[2][6];
        #pragma unroll
        for (int n = 0; n < 6; ++n) {
            const float bv = hb1[(n >> 1) * 32 + (n & 1) * 16 + c];
            f32x4 t = {bv, bv, bv, bv};
            ah[0][n] = t; ah[1][n] = t;
        }
        #pragma unroll
        for (int ks = 0; ks < 2; ++ks) {
            const f16x8 a0 = ld_frag<2>(ACT1, 64, waveRow,      ks * 32);
            const f16x8 a1 = ld_frag<2>(ACT1, 64, waveRow + 16, ks * 32);
            #pragma unroll
            for (int n = 0; n < 6; ++n) {
                const int head = n >> 1;
                const f16* hw = (head == 0) ? (W + 4096) : (head == 1) ? (W + 6144) : G;
                const f16x8 b = ld_frag<0>(hw, 64, (n & 1) * 16, ks * 32);
                ah[0][n] = MFMA16(a0, b, ah[0][n]);
                ah[1][n] = MFMA16(a1, b, ah[1][n]);
            }
        }
        const float hb2_0 = hb2[0], hb2_1 = hb2[1], hb2_2 = hb2[2];
        #pragma unroll
        for (int m = 0; m < 2; ++m) {
            f32x4 ph[3] = {{0,0,0,0},{0,0,0,0},{0,0,0,0}};
            #pragma unroll
            for (int n = 0; n < 6; ++n) {
                const int head = n >> 1;
                const int j = (n & 1) * 16 + c;
                const float w2v = hw2[head * 32 + j];
                #pragma unroll
                for (int g = 0; g < 4; ++g)
                    ph[head][g] += silu_f(ah[m][n][g]) * w2v;
            }
            #pragma unroll
            for (int h = 0; h < 3; ++h) ph[h] = reduce16(ph[h]);
            #pragma unroll
            for (int g = 0; g < 4; ++g) {
                const long row = blockRow + waveRow + m * 16 + ((lane >> 4) << 2) + g;
                if (c < 3) {
                    const float r0 = ph[0][g] + hb2_0;
                    const float r1 = ph[1][g] + hb2_1;
                    const float r2 = ph[2][g] + hb2_2;
                    out[row * 3 + c] = (c == 0) ? r0 : ((c == 1) ? r1 : r2);
                }
            }
        }
    }
}

extern "C" void kernel_launch(void* const* d_in, const int* in_sizes, int n_in,
                              void* d_out, int out_size, void* d_ws, size_t ws_size,
                              hipStream_t stream) {
    const float* x    = (const float*)d_in[0];
    const float* w1   = (const float*)d_in[1];
    const float* b1   = (const float*)d_in[2];
    const float* lng  = (const float*)d_in[3];
    const float* lnb  = (const float*)d_in[4];
    const float* w2   = (const float*)d_in[5];
    const float* b2   = (const float*)d_in[6];
    const float* ew1  = (const float*)d_in[7];
    const float* eb1  = (const float*)d_in[8];
    const float* ew2  = (const float*)d_in[9];
    const float* eb2  = (const float*)d_in[10];
    const float* gw1  = (const float*)d_in[11];
    const float* gb1  = (const float*)d_in[12];
    const float* gw2  = (const float*)d_in[13];
    const float* gb2  = (const float*)d_in[14];
    const float* sw   = (const float*)d_in[15];
    const float* sb   = (const float*)d_in[16];
    const float* hw1  = (const float*)d_in[17];
    const float* hb1  = (const float*)d_in[18];
    const float* hw2  = (const float*)d_in[19];
    const float* hb2  = (const float*)d_in[20];
    float* out = (float*)d_out;
    f16* ws = (f16*)d_ws;

    hipLaunchKernelGGL(prep_weights, dim3(64), dim3(256), 0, stream,
                       w1, w2, gw1, ew1, ew2, sw, hw1, ws);

    const int B = in_sizes[0] / 256;
    const int grid = B / 128;
    hipLaunchKernelGGL(fused_net_mfma, dim3(grid), dim3(256), 0, stream,
                       x, ws, b1, lng, lnb, b2, eb1, eb2, gb1, gw2, gb2,
                       sb, hb1, hw2, hb2, out);
}